// Round 8
// baseline (44.662 us; speedup 1.0000x reference)
//
#include <hip/hip_runtime.h>
#include <hip/hip_bf16.h>

#define TV    512
#define TL    64
#define D_    512
#define BKT   64
#define VROWS 64
#define NCHUNK (TV/VROWS)   // 8
#define NKT   (D_/BKT)      // 8

typedef __attribute__((ext_vector_type(8))) short bf16x8;
typedef __attribute__((ext_vector_type(4))) float f32x4;

__global__ __launch_bounds__(512, 8) void chamfer_main(
    const float* __restrict__ vf, const float* __restrict__ lf,
    const float* __restrict__ mv, const float* __restrict__ ml,
    float* __restrict__ pcol, float* __restrict__ psum)
{
  // XCD-aware decode: all 8 chunks of a batch land on the same XCD.
  const int lin   = blockIdx.x;          // 0..1023
  const int xcd   = lin & 7;
  const int kk    = lin >> 3;            // 0..127
  const int chunk = kk & 7;
  const int b     = ((kk >> 3) << 3) | xcd;   // bijective over 0..127

  const int t     = threadIdx.x;         // 0..511
  const int w     = t >> 6;              // 0..7
  const int lane  = t & 63;
  const int g     = lane >> 4;
  const int c15   = lane & 15;
  const int rt    = w & 3;               // row-tile 0..3 (16 rows each)
  const int ch    = w >> 2;              // col-half 0..1 (32 cols each)

  // Only L goes through LDS (shared by all 8 waves, reused). V goes
  // global -> register -> cvt -> MFMA A-fragment directly.
  __shared__ __align__(16) short ll[TL * BKT];   // 8 KiB swizzled bf16
  __shared__ float normv_s[VROWS];
  __shared__ float norml_s[TL];
  __shared__ float mvs[VROWS];
  __shared__ float mls[TL];
  __shared__ float rowp[8][16];
  __shared__ float colp[8][32];

  const int v0 = chunk * VROWS;
  const float* vbase = vf + ((size_t)b * TV + v0) * D_;
  const float* lbase = lf + (size_t)b * TL * D_;
  // A-fragment source: row = rt*16 + c15, k-offset g*8 within each 32-k step
  const float* vfrag = vbase + (size_t)(rt * 16 + c15) * D_ + g * 8;
  // L staging source: row = t>>3, chunk kc = t&7 (8 floats)
  const int lrow = t >> 3, lkc = t & 7;
  const float* lsrc = lbase + (size_t)lrow * D_ + lkc * 8;

  if (t < VROWS)                mvs[t]        = mv[(size_t)b * TV + v0 + t];
  else if (t < VROWS + TL)      mls[t - VROWS] = ml[(size_t)b * TL + (t - VROWS)];

  f32x4 acc[2];
  acc[0] = (f32x4){0.f, 0.f, 0.f, 0.f};
  acc[1] = (f32x4){0.f, 0.f, 0.f, 0.f};

  float nvacc = 0.f;   // row rt*16+c15 partial (ch==0 waves only)
  float nlacc = 0.f;   // staging row lrow partial

  for (int kt = 0; kt < NKT; ++kt) {
    // ---- stage L tile (64 x 64, bf16, swizzled): 2 float4 per thread ----
    {
      const float4* s = (const float4*)(lsrc + kt * BKT);
      float4 a = s[0], bq = s[1];
      nlacc += a.x*a.x + a.y*a.y + a.z*a.z + a.w*a.w
             + bq.x*bq.x + bq.y*bq.y + bq.z*bq.z + bq.w*bq.w;
      union { bf16x8 v8; __hip_bfloat162 h[4]; } u;
      u.h[0] = __float22bfloat162_rn(make_float2(a.x, a.y));
      u.h[1] = __float22bfloat162_rn(make_float2(a.z, a.w));
      u.h[2] = __float22bfloat162_rn(make_float2(bq.x, bq.y));
      u.h[3] = __float22bfloat162_rn(make_float2(bq.z, bq.w));
      int off = (lrow * 128 + lkc * 16) ^ ((lrow & 7) << 4);
      *(bf16x8*)((char*)ll + off) = u.v8;
    }
    __syncthreads();
    // ---- compute: V direct-load A-fragments + LDS B-fragments ----
    #pragma unroll
    for (int ks = 0; ks < 2; ks++) {
      const float4* s = (const float4*)(vfrag + kt * BKT + ks * 32);
      float4 a = s[0], bq = s[1];
      if (ch == 0)
        nvacc += a.x*a.x + a.y*a.y + a.z*a.z + a.w*a.w
               + bq.x*bq.x + bq.y*bq.y + bq.z*bq.z + bq.w*bq.w;
      union { bf16x8 v8; __hip_bfloat162 h[4]; } u;
      u.h[0] = __float22bfloat162_rn(make_float2(a.x, a.y));
      u.h[1] = __float22bfloat162_rn(make_float2(a.z, a.w));
      u.h[2] = __float22bfloat162_rn(make_float2(bq.x, bq.y));
      u.h[3] = __float22bfloat162_rn(make_float2(bq.z, bq.w));
      bf16x8 bfr[2];
      #pragma unroll
      for (int n = 0; n < 2; n++) {
        int row = ch * 32 + n * 16 + c15;
        int off = (row * 128 + ks * 64 + g * 16) ^ ((row & 7) << 4);
        bfr[n] = *(const bf16x8*)((const char*)ll + off);
      }
      #pragma unroll
      for (int n = 0; n < 2; n++)
        acc[n] = __builtin_amdgcn_mfma_f32_16x16x32_bf16(u.v8, bfr[n], acc[n], 0, 0, 0);
    }
    __syncthreads();   // before next tile overwrites ll
  }

  // ---- norm reductions ----
  if (ch == 0) {
    float s = nvacc;
    s += __shfl_xor(s, 16);
    s += __shfl_xor(s, 32);
    if (g == 0) normv_s[rt * 16 + c15] = s;
  }
  {
    float s2 = nlacc;
    s2 += __shfl_xor(s2, 1); s2 += __shfl_xor(s2, 2); s2 += __shfl_xor(s2, 4);
    if ((t & 7) == 0) norml_s[lrow] = s2;
  }
  __syncthreads();

  // ---- epilogue: pd + masking, row/col mins ----
  const float BIG = 3.0e38f;
  float pdv[2][4];   // [n][j]
  #pragma unroll
  for (int n = 0; n < 2; n++)
    #pragma unroll
    for (int j = 0; j < 4; j++) {
      int row = rt * 16 + g * 4 + j;
      int col = ch * 32 + n * 16 + c15;
      float pd = normv_s[row] + norml_s[col] - 2.0f * acc[n][j];
      bool valid = (mvs[row] != 0.f) && (mls[col] != 0.f);
      pdv[n][j] = valid ? pd : BIG;
    }

  // per-wave row-min over its 32 cols
  #pragma unroll
  for (int j = 0; j < 4; j++) {
    float rm = fminf(pdv[0][j], pdv[1][j]);
    rm = fminf(rm, __shfl_xor(rm, 1));
    rm = fminf(rm, __shfl_xor(rm, 2));
    rm = fminf(rm, __shfl_xor(rm, 4));
    rm = fminf(rm, __shfl_xor(rm, 8));
    if (c15 == 0) rowp[w][g * 4 + j] = rm;
  }
  // per-wave col-min over its 16 rows
  #pragma unroll
  for (int n = 0; n < 2; n++) {
    float cm = fminf(fminf(pdv[n][0], pdv[n][1]),
                     fminf(pdv[n][2], pdv[n][3]));
    cm = fminf(cm, __shfl_xor(cm, 16));
    cm = fminf(cm, __shfl_xor(cm, 32));
    if (g == 0) colp[w][n * 16 + c15] = cm;
  }
  __syncthreads();

  if (t < 64) {
    // rows: combine col-halves (waves rt and rt+4), masked sum
    int row = t;
    float rm = fminf(rowp[row >> 4][row & 15], rowp[(row >> 4) + 4][row & 15]);
    float sl = (mvs[row] != 0.f) ? rm : 0.f;
    #pragma unroll
    for (int s = 1; s < 64; s <<= 1) sl += __shfl_xor(sl, s);
    if (t == 0) psum[(size_t)b * NCHUNK + chunk] = sl;
    // cols: combine the 4 row-tiles of this col-half
    int col = t;
    int chh = col >> 5, lc = col & 31;
    float cm = fminf(fminf(colp[chh * 4 + 0][lc], colp[chh * 4 + 1][lc]),
                     fminf(colp[chh * 4 + 2][lc], colp[chh * 4 + 3][lc]));
    pcol[((size_t)b * NCHUNK + chunk) * TL + col] = cm;
  }
}

__global__ __launch_bounds__(64) void chamfer_fin(
    const float* __restrict__ pcol, const float* __restrict__ psum,
    const float* __restrict__ mv, const float* __restrict__ ml,
    float* __restrict__ out)
{
  int b = blockIdx.x;
  int l = threadIdx.x;
  float cm = pcol[((size_t)b * NCHUNK + 0) * 64 + l];
  #pragma unroll
  for (int i = 1; i < NCHUNK; i++)
    cm = fminf(cm, pcol[((size_t)b * NCHUNK + i) * 64 + l]);
  float mlv = ml[(size_t)b * 64 + l];
  float sl = (mlv != 0.f) ? cm : 0.f;
  float nl = mlv;
  float nv = 0.f;
  #pragma unroll
  for (int i = 0; i < 8; i++) nv += mv[(size_t)b * 512 + l * 8 + i];
  float sv = (l < NCHUNK) ? psum[(size_t)b * NCHUNK + l] : 0.f;
  #pragma unroll
  for (int s = 1; s < 64; s <<= 1) {
    sl += __shfl_xor(sl, s);
    nl += __shfl_xor(nl, s);
    nv += __shfl_xor(nv, s);
    sv += __shfl_xor(sv, s);
  }
  if (l == 0) out[b] = sl / nl + sv / nv;
}

extern "C" void kernel_launch(void* const* d_in, const int* in_sizes, int n_in,
                              void* d_out, int out_size, void* d_ws, size_t ws_size,
                              hipStream_t stream) {
  const float* vf = (const float*)d_in[0];
  const float* lf = (const float*)d_in[1];
  const float* mv = (const float*)d_in[2];
  const float* ml = (const float*)d_in[3];
  float* out  = (float*)d_out;
  float* pcol = (float*)d_ws;                       // [128][8][64]
  float* psum = pcol + 128 * NCHUNK * 64;           // [128][8]
  chamfer_main<<<128 * NCHUNK, 512, 0, stream>>>(vf, lf, mv, ml, pcol, psum);
  chamfer_fin<<<128, 64, 0, stream>>>(pcol, psum, mv, ml, out);
}

// Round 9
// 33.066 us; speedup vs baseline: 1.3507x; 1.3507x over previous
//
#include <hip/hip_runtime.h>
#include <hip/hip_bf16.h>

#define TV    512
#define TL    64
#define D_    512
#define BKT   64
#define VROWS 128
#define NCHUNK (TV/VROWS)   // 4
#define NKT   (D_/BKT)      // 8

typedef __attribute__((ext_vector_type(8))) short bf16x8;
typedef __attribute__((ext_vector_type(4))) float f32x4;

__global__ __launch_bounds__(512, 4) void chamfer_main(
    const float* __restrict__ vf, const float* __restrict__ lf,
    const float* __restrict__ mv, const float* __restrict__ ml,
    float* __restrict__ pcol, float* __restrict__ psum)
{
  // XCD-aware decode: all 4 chunks of a batch land on the same XCD.
  const int lin   = blockIdx.x;          // 0..511
  const int xcd   = lin & 7;
  const int kk    = lin >> 3;            // 0..63
  const int chunk = kk & 3;
  const int b     = ((kk >> 2) << 3) | xcd;   // bijective over 0..127

  const int t     = threadIdx.x;         // 0..511
  const int w     = t >> 6;              // 0..7
  const int lane  = t & 63;
  const int g     = lane >> 4;
  const int c15   = lane & 15;
  const int srow  = t >> 3;              // staging row base 0..63
  const int skc   = t & 7;               // staging k-chunk (8 floats)

  // single-buffered swizzled bf16 tiles (R4 idiom, scaled to 128 v-rows)
  __shared__ __align__(16) short lv[VROWS * BKT];  // 16 KiB
  __shared__ __align__(16) short ll[TL * BKT];     // 8 KiB
  __shared__ float normv_s[VROWS];
  __shared__ float norml_s[TL];
  __shared__ float mvs[VROWS];
  __shared__ float mls[TL];
  __shared__ float wavecol[8][TL];
  __shared__ float wavesum[8];

  const int v0 = chunk * VROWS;
  const float* vbase = vf + ((size_t)b * TV + v0) * D_;
  const float* lbase = lf + (size_t)b * TL * D_;

  if (t < VROWS)                mvs[t]        = mv[(size_t)b * TV + v0 + t];
  else if (t < VROWS + TL)      mls[t - VROWS] = ml[(size_t)b * TL + (t - VROWS)];

  f32x4 acc[4];
  #pragma unroll
  for (int n = 0; n < 4; n++) acc[n] = (f32x4){0.f, 0.f, 0.f, 0.f};

  float nvacc[2] = {0.f, 0.f};  // V rows srow, srow+64
  float nlacc = 0.f;            // L row srow

  for (int kt = 0; kt < NKT; ++kt) {
    // ---- stage V tile 128x64 (two 64-row halves) + L tile 64x64 ----
    // 8 consecutive lanes cover 128B of one row: fully coalesced.
    #pragma unroll
    for (int p = 0; p < 2; p++) {
      int row = p * 64 + srow;
      int off = (row * 128 + skc * 16) ^ ((row & 7) << 4);
      const float4* sv_ = (const float4*)(vbase + (size_t)row * D_ + kt * BKT + skc * 8);
      float4 a = sv_[0], bq = sv_[1];
      nvacc[p] += a.x*a.x + a.y*a.y + a.z*a.z + a.w*a.w
                + bq.x*bq.x + bq.y*bq.y + bq.z*bq.z + bq.w*bq.w;
      union { bf16x8 v8; __hip_bfloat162 h[4]; } u;
      u.h[0] = __float22bfloat162_rn(make_float2(a.x, a.y));
      u.h[1] = __float22bfloat162_rn(make_float2(a.z, a.w));
      u.h[2] = __float22bfloat162_rn(make_float2(bq.x, bq.y));
      u.h[3] = __float22bfloat162_rn(make_float2(bq.z, bq.w));
      *(bf16x8*)((char*)lv + off) = u.v8;
    }
    {
      int row = srow;
      int off = (row * 128 + skc * 16) ^ ((row & 7) << 4);
      const float4* sl_ = (const float4*)(lbase + (size_t)row * D_ + kt * BKT + skc * 8);
      float4 c = sl_[0], dq = sl_[1];
      nlacc += c.x*c.x + c.y*c.y + c.z*c.z + c.w*c.w
             + dq.x*dq.x + dq.y*dq.y + dq.z*dq.z + dq.w*dq.w;
      union { bf16x8 v8; __hip_bfloat162 h[4]; } u2;
      u2.h[0] = __float22bfloat162_rn(make_float2(c.x, c.y));
      u2.h[1] = __float22bfloat162_rn(make_float2(c.z, c.w));
      u2.h[2] = __float22bfloat162_rn(make_float2(dq.x, dq.y));
      u2.h[3] = __float22bfloat162_rn(make_float2(dq.z, dq.w));
      *(bf16x8*)((char*)ll + off) = u2.v8;
    }
    __syncthreads();
    // ---- MFMA: wave w owns rows w*16..w*16+15; 2 k-steps of 32 ----
    #pragma unroll
    for (int ks = 0; ks < 2; ks++) {
      bf16x8 afr, bfr[4];
      {
        int row = w * 16 + c15;
        int off = (row * 128 + ks * 64 + g * 16) ^ ((row & 7) << 4);
        afr = *(const bf16x8*)((const char*)lv + off);
      }
      #pragma unroll
      for (int n = 0; n < 4; n++) {
        int row = n * 16 + c15;
        int off = (row * 128 + ks * 64 + g * 16) ^ ((row & 7) << 4);
        bfr[n] = *(const bf16x8*)((const char*)ll + off);
      }
      #pragma unroll
      for (int n = 0; n < 4; n++)
        acc[n] = __builtin_amdgcn_mfma_f32_16x16x32_bf16(afr, bfr[n], acc[n], 0, 0, 0);
    }
    __syncthreads();
  }

  // ---- row-norm reductions (8 consecutive lanes share a staged row) ----
  #pragma unroll
  for (int p = 0; p < 2; p++) {
    float s = nvacc[p];
    s += __shfl_xor(s, 1); s += __shfl_xor(s, 2); s += __shfl_xor(s, 4);
    if ((t & 7) == 0) normv_s[p * 64 + srow] = s;
  }
  {
    float s2 = nlacc;
    s2 += __shfl_xor(s2, 1); s2 += __shfl_xor(s2, 2); s2 += __shfl_xor(s2, 4);
    if ((t & 7) == 0) norml_s[srow] = s2;
  }
  __syncthreads();

  // ---- epilogue: pd + masking, row/col mins ----
  const float BIG = 3.0e38f;
  float pdv[4][4];   // [n][j]
  #pragma unroll
  for (int n = 0; n < 4; n++)
    #pragma unroll
    for (int j = 0; j < 4; j++) {
      int row = w * 16 + g * 4 + j;
      int col = n * 16 + c15;
      float pd = normv_s[row] + norml_s[col] - 2.0f * acc[n][j];
      bool valid = (mvs[row] != 0.f) && (mls[col] != 0.f);
      pdv[n][j] = valid ? pd : BIG;
    }

  // row mins (over all 64 cols) -> masked sum over this wave's 16 rows
  float svl = 0.f;
  #pragma unroll
  for (int j = 0; j < 4; j++) {
    float rm = fminf(fminf(pdv[0][j], pdv[1][j]),
                     fminf(pdv[2][j], pdv[3][j]));
    rm = fminf(rm, __shfl_xor(rm, 1));
    rm = fminf(rm, __shfl_xor(rm, 2));
    rm = fminf(rm, __shfl_xor(rm, 4));
    rm = fminf(rm, __shfl_xor(rm, 8));
    int row = w * 16 + g * 4 + j;
    if (c15 == 0 && mvs[row] != 0.f) svl += rm;
  }
  svl += __shfl_xor(svl, 16);
  svl += __shfl_xor(svl, 32);
  if (lane == 0) wavesum[w] = svl;

  // col mins over this wave's 16 rows
  #pragma unroll
  for (int n = 0; n < 4; n++) {
    float cm = fminf(fminf(pdv[n][0], pdv[n][1]),
                     fminf(pdv[n][2], pdv[n][3]));
    cm = fminf(cm, __shfl_xor(cm, 16));
    cm = fminf(cm, __shfl_xor(cm, 32));
    if (g == 0) wavecol[w][n * 16 + c15] = cm;
  }
  __syncthreads();

  if (t < TL) {
    float cm = wavecol[0][t];
    #pragma unroll
    for (int wv = 1; wv < 8; wv++) cm = fminf(cm, wavecol[wv][t]);
    pcol[((size_t)b * NCHUNK + chunk) * TL + t] = cm;
  }
  if (t == 0) {
    float s = 0.f;
    #pragma unroll
    for (int wv = 0; wv < 8; wv++) s += wavesum[wv];
    psum[(size_t)b * NCHUNK + chunk] = s;
  }
}

__global__ __launch_bounds__(64) void chamfer_fin(
    const float* __restrict__ pcol, const float* __restrict__ psum,
    const float* __restrict__ mv, const float* __restrict__ ml,
    float* __restrict__ out)
{
  int b = blockIdx.x;
  int l = threadIdx.x;
  float cm = pcol[((size_t)b * NCHUNK + 0) * 64 + l];
  #pragma unroll
  for (int i = 1; i < NCHUNK; i++)
    cm = fminf(cm, pcol[((size_t)b * NCHUNK + i) * 64 + l]);
  float mlv = ml[(size_t)b * 64 + l];
  float sl = (mlv != 0.f) ? cm : 0.f;
  float nl = mlv;
  float nv = 0.f;
  #pragma unroll
  for (int i = 0; i < 8; i++) nv += mv[(size_t)b * 512 + l * 8 + i];
  float sv = (l < NCHUNK) ? psum[(size_t)b * NCHUNK + l] : 0.f;
  #pragma unroll
  for (int s = 1; s < 64; s <<= 1) {
    sl += __shfl_xor(sl, s);
    nl += __shfl_xor(nl, s);
    nv += __shfl_xor(nv, s);
    sv += __shfl_xor(sv, s);
  }
  if (l == 0) out[b] = sl / nl + sv / nv;
}

extern "C" void kernel_launch(void* const* d_in, const int* in_sizes, int n_in,
                              void* d_out, int out_size, void* d_ws, size_t ws_size,
                              hipStream_t stream) {
  const float* vf = (const float*)d_in[0];
  const float* lf = (const float*)d_in[1];
  const float* mv = (const float*)d_in[2];
  const float* ml = (const float*)d_in[3];
  float* out  = (float*)d_out;
  float* pcol = (float*)d_ws;                       // [128][4][64]
  float* psum = pcol + 128 * NCHUNK * 64;           // [128][4]
  chamfer_main<<<128 * NCHUNK, 512, 0, stream>>>(vf, lf, mv, ml, pcol, psum);
  chamfer_fin<<<128, 64, 0, stream>>>(pcol, psum, mv, ml, out);
}

// Round 10
// 32.700 us; speedup vs baseline: 1.3658x; 1.0112x over previous
//
#include <hip/hip_runtime.h>
#include <hip/hip_bf16.h>

#define TV    512
#define TL    64
#define D_    512
#define BKT   64
#define VROWS 64
#define NCHUNK (TV/VROWS)   // 8
#define NKT   (D_/BKT)      // 8

typedef __attribute__((ext_vector_type(8))) short bf16x8;
typedef __attribute__((ext_vector_type(4))) float f32x4;

__global__ __launch_bounds__(512, 8) void chamfer_main(
    const float* __restrict__ vf, const float* __restrict__ lf,
    const float* __restrict__ mv, const float* __restrict__ ml,
    float* __restrict__ pcol, float* __restrict__ psum)
{
  // XCD-aware decode: all 8 chunks of a batch land on the same XCD.
  const int lin   = blockIdx.x;          // 0..1023
  const int xcd   = lin & 7;
  const int kk    = lin >> 3;            // 0..127
  const int chunk = kk & 7;
  const int b     = ((kk >> 3) << 3) | xcd;   // bijective over 0..127

  const int t     = threadIdx.x;         // 0..511
  const int w     = t >> 6;              // 0..7
  const int lane  = t & 63;
  const int g     = lane >> 4;
  const int c15   = lane & 15;
  const int rt    = w & 3;               // row-tile 0..3 (16 rows)
  const int ch    = w >> 2;              // col-half 0..1 (32 cols)
  const int srow  = t >> 3;              // staging row 0..63
  const int skc   = t & 7;               // staging k-chunk (8 floats)

  // single-buffered swizzled bf16 tiles, R4 staging idiom split over 512 thr
  __shared__ __align__(16) short lv[VROWS * BKT];  // 8 KiB
  __shared__ __align__(16) short ll[TL * BKT];     // 8 KiB
  __shared__ float normv_s[VROWS];
  __shared__ float norml_s[TL];
  __shared__ float mvs[VROWS];
  __shared__ float mls[TL];
  __shared__ float rowp[8][16];
  __shared__ float colp[8][32];

  const int v0 = chunk * VROWS;
  const float* vbase = vf + ((size_t)b * TV + v0) * D_;
  const float* lbase = lf + (size_t)b * TL * D_;
  const float* vsrc = vbase + (size_t)srow * D_ + skc * 8;
  const float* lsrc = lbase + (size_t)srow * D_ + skc * 8;

  if (t < VROWS)                mvs[t]        = mv[(size_t)b * TV + v0 + t];
  else if (t < VROWS + TL)      mls[t - VROWS] = ml[(size_t)b * TL + (t - VROWS)];

  f32x4 acc[2];
  acc[0] = (f32x4){0.f, 0.f, 0.f, 0.f};
  acc[1] = (f32x4){0.f, 0.f, 0.f, 0.f};

  float nvacc = 0.f;   // V row srow partial
  float nlacc = 0.f;   // L row srow partial

  const int soff = (srow * 128 + skc * 16) ^ ((srow & 7) << 4);

  for (int kt = 0; kt < NKT; ++kt) {
    // ---- stage V and L tiles (64 x 64 each, bf16, swizzled) ----
    // 8 consecutive lanes cover 128B of one row: fully coalesced.
    {
      const float4* sv_ = (const float4*)(vsrc + kt * BKT);
      float4 a = sv_[0], bq = sv_[1];
      nvacc += a.x*a.x + a.y*a.y + a.z*a.z + a.w*a.w
             + bq.x*bq.x + bq.y*bq.y + bq.z*bq.z + bq.w*bq.w;
      union { bf16x8 v8; __hip_bfloat162 h[4]; } u;
      u.h[0] = __float22bfloat162_rn(make_float2(a.x, a.y));
      u.h[1] = __float22bfloat162_rn(make_float2(a.z, a.w));
      u.h[2] = __float22bfloat162_rn(make_float2(bq.x, bq.y));
      u.h[3] = __float22bfloat162_rn(make_float2(bq.z, bq.w));
      *(bf16x8*)((char*)lv + soff) = u.v8;

      const float4* sl_ = (const float4*)(lsrc + kt * BKT);
      float4 c = sl_[0], dq = sl_[1];
      nlacc += c.x*c.x + c.y*c.y + c.z*c.z + c.w*c.w
             + dq.x*dq.x + dq.y*dq.y + dq.z*dq.z + dq.w*dq.w;
      union { bf16x8 v8; __hip_bfloat162 h[4]; } u2;
      u2.h[0] = __float22bfloat162_rn(make_float2(c.x, c.y));
      u2.h[1] = __float22bfloat162_rn(make_float2(c.z, c.w));
      u2.h[2] = __float22bfloat162_rn(make_float2(dq.x, dq.y));
      u2.h[3] = __float22bfloat162_rn(make_float2(dq.z, dq.w));
      *(bf16x8*)((char*)ll + soff) = u2.v8;
    }
    __syncthreads();
    // ---- MFMA: wave = (row-tile rt, col-half ch); 2 k-steps of 32 ----
    #pragma unroll
    for (int ks = 0; ks < 2; ks++) {
      bf16x8 afr, bfr[2];
      {
        int row = rt * 16 + c15;
        int off = (row * 128 + ks * 64 + g * 16) ^ ((row & 7) << 4);
        afr = *(const bf16x8*)((const char*)lv + off);
      }
      #pragma unroll
      for (int n = 0; n < 2; n++) {
        int row = ch * 32 + n * 16 + c15;
        int off = (row * 128 + ks * 64 + g * 16) ^ ((row & 7) << 4);
        bfr[n] = *(const bf16x8*)((const char*)ll + off);
      }
      #pragma unroll
      for (int n = 0; n < 2; n++)
        acc[n] = __builtin_amdgcn_mfma_f32_16x16x32_bf16(afr, bfr[n], acc[n], 0, 0, 0);
    }
    __syncthreads();
  }

  // ---- row-norm reductions (8 consecutive lanes share a staged row) ----
  {
    float s = nvacc;
    s += __shfl_xor(s, 1); s += __shfl_xor(s, 2); s += __shfl_xor(s, 4);
    if ((t & 7) == 0) normv_s[srow] = s;
    float s2 = nlacc;
    s2 += __shfl_xor(s2, 1); s2 += __shfl_xor(s2, 2); s2 += __shfl_xor(s2, 4);
    if ((t & 7) == 0) norml_s[srow] = s2;
  }
  __syncthreads();

  // ---- epilogue: pd + masking, row/col mins ----
  const float BIG = 3.0e38f;
  float pdv[2][4];   // [n][j]
  #pragma unroll
  for (int n = 0; n < 2; n++)
    #pragma unroll
    for (int j = 0; j < 4; j++) {
      int row = rt * 16 + g * 4 + j;
      int col = ch * 32 + n * 16 + c15;
      float pd = normv_s[row] + norml_s[col] - 2.0f * acc[n][j];
      bool valid = (mvs[row] != 0.f) && (mls[col] != 0.f);
      pdv[n][j] = valid ? pd : BIG;
    }

  // per-wave row-min over its 32 cols
  #pragma unroll
  for (int j = 0; j < 4; j++) {
    float rm = fminf(pdv[0][j], pdv[1][j]);
    rm = fminf(rm, __shfl_xor(rm, 1));
    rm = fminf(rm, __shfl_xor(rm, 2));
    rm = fminf(rm, __shfl_xor(rm, 4));
    rm = fminf(rm, __shfl_xor(rm, 8));
    if (c15 == 0) rowp[w][g * 4 + j] = rm;
  }
  // per-wave col-min over its 16 rows
  #pragma unroll
  for (int n = 0; n < 2; n++) {
    float cm = fminf(fminf(pdv[n][0], pdv[n][1]),
                     fminf(pdv[n][2], pdv[n][3]));
    cm = fminf(cm, __shfl_xor(cm, 16));
    cm = fminf(cm, __shfl_xor(cm, 32));
    if (g == 0) colp[w][n * 16 + c15] = cm;
  }
  __syncthreads();

  if (t < 64) {
    // rows: combine the two col-halves, masked sum over 64 rows
    int row = t;
    float rm = fminf(rowp[row >> 4][row & 15], rowp[(row >> 4) + 4][row & 15]);
    float sl = (mvs[row] != 0.f) ? rm : 0.f;
    #pragma unroll
    for (int s = 1; s < 64; s <<= 1) sl += __shfl_xor(sl, s);
    if (t == 0) psum[(size_t)b * NCHUNK + chunk] = sl;
    // cols: combine the 4 row-tiles of this col-half
    int col = t;
    int chh = col >> 5, lc = col & 31;
    float cm = fminf(fminf(colp[chh * 4 + 0][lc], colp[chh * 4 + 1][lc]),
                     fminf(colp[chh * 4 + 2][lc], colp[chh * 4 + 3][lc]));
    pcol[((size_t)b * NCHUNK + chunk) * TL + col] = cm;
  }
}

__global__ __launch_bounds__(64) void chamfer_fin(
    const float* __restrict__ pcol, const float* __restrict__ psum,
    const float* __restrict__ mv, const float* __restrict__ ml,
    float* __restrict__ out)
{
  int b = blockIdx.x;
  int l = threadIdx.x;
  float cm = pcol[((size_t)b * NCHUNK + 0) * 64 + l];
  #pragma unroll
  for (int i = 1; i < NCHUNK; i++)
    cm = fminf(cm, pcol[((size_t)b * NCHUNK + i) * 64 + l]);
  float mlv = ml[(size_t)b * 64 + l];
  float sl = (mlv != 0.f) ? cm : 0.f;
  float nl = mlv;
  float nv = 0.f;
  #pragma unroll
  for (int i = 0; i < 8; i++) nv += mv[(size_t)b * 512 + l * 8 + i];
  float sv = (l < NCHUNK) ? psum[(size_t)b * NCHUNK + l] : 0.f;
  #pragma unroll
  for (int s = 1; s < 64; s <<= 1) {
    sl += __shfl_xor(sl, s);
    nl += __shfl_xor(nl, s);
    nv += __shfl_xor(nv, s);
    sv += __shfl_xor(sv, s);
  }
  if (l == 0) out[b] = sl / nl + sv / nv;
}

extern "C" void kernel_launch(void* const* d_in, const int* in_sizes, int n_in,
                              void* d_out, int out_size, void* d_ws, size_t ws_size,
                              hipStream_t stream) {
  const float* vf = (const float*)d_in[0];
  const float* lf = (const float*)d_in[1];
  const float* mv = (const float*)d_in[2];
  const float* ml = (const float*)d_in[3];
  float* out  = (float*)d_out;
  float* pcol = (float*)d_ws;                       // [128][8][64]
  float* psum = pcol + 128 * NCHUNK * 64;           // [128][8]
  chamfer_main<<<128 * NCHUNK, 512, 0, stream>>>(vf, lf, mv, ml, pcol, psum);
  chamfer_fin<<<128, 64, 0, stream>>>(pcol, psum, mv, ml, out);
}